// Round 1
// baseline (253.589 us; speedup 1.0000x reference)
//
#include <hip/hip_runtime.h>

#define S_ 2304   // 48*48

typedef unsigned short u16;
typedef __attribute__((ext_vector_type(8))) short bf16x8;
typedef __attribute__((ext_vector_type(4))) float f32x4;

static __device__ __forceinline__ u16 f2bf(float x) {
  union { float f; unsigned u; } v; v.f = x;
  unsigned r = v.u + 0x7FFFu + ((v.u >> 16) & 1u);
  return (u16)(r >> 16);
}
static __device__ __forceinline__ float bf2f(u16 h) {
  union { unsigned u; float f; } v; v.u = ((unsigned)h) << 16; return v.f;
}

// ---------------------------------------------------------------------------
// GEMM (1x1 conv): Out[b][m][s] = sum_k Wm[m][k] * X[b][k][s] + bias[m]
// K fixed at 256. Tile 64(m) x 128(n), 256 threads, 4x8 micro-tile.
// ---------------------------------------------------------------------------
__global__ __launch_bounds__(256) void gemm1x1_kernel(
    const float* __restrict__ Wm, const float* __restrict__ bias,
    const float* __restrict__ X, float* __restrict__ Out, int M)
{
  __shared__ float wT[32][68];    // [k][m], padded
  __shared__ float xT[32][136];   // [k][n], padded
  const int b  = blockIdx.z;
  const int m0 = blockIdx.y * 64;
  const int n0 = blockIdx.x * 128;
  const float* Xb = X + (size_t)b * 256 * S_;
  float* Ob = Out + (size_t)b * M * S_;
  const int tid = threadIdx.x;
  const int mg = tid >> 4, ng = tid & 15;
  float acc[4][8];
#pragma unroll
  for (int i = 0; i < 4; i++)
#pragma unroll
    for (int j = 0; j < 8; j++) acc[i][j] = 0.f;

  for (int k0 = 0; k0 < 256; k0 += 32) {
#pragma unroll
    for (int rep = 0; rep < 2; rep++) {
      int id = tid + rep * 256;
      int row = id >> 3, cg = (id & 7) * 4;
      float4 w4 = *(const float4*)&Wm[(size_t)(m0 + row) * 256 + k0 + cg];
      wT[cg + 0][row] = w4.x; wT[cg + 1][row] = w4.y;
      wT[cg + 2][row] = w4.z; wT[cg + 3][row] = w4.w;
    }
#pragma unroll
    for (int rep = 0; rep < 4; rep++) {
      int id = tid + rep * 256;
      int row = id >> 5, cg = (id & 31) * 4;
      *(float4*)&xT[row][cg] = *(const float4*)&Xb[(size_t)(k0 + row) * S_ + n0 + cg];
    }
    __syncthreads();
#pragma unroll
    for (int k = 0; k < 32; k++) {
      float4 a4 = *(float4*)&wT[k][mg * 4];
      float4 x0 = *(float4*)&xT[k][ng * 4];
      float4 x1 = *(float4*)&xT[k][64 + ng * 4];
      float av[4] = {a4.x, a4.y, a4.z, a4.w};
      float xv[8] = {x0.x, x0.y, x0.z, x0.w, x1.x, x1.y, x1.z, x1.w};
#pragma unroll
      for (int mi = 0; mi < 4; mi++)
#pragma unroll
        for (int ni = 0; ni < 8; ni++) acc[mi][ni] += av[mi] * xv[ni];
    }
    __syncthreads();
  }
#pragma unroll
  for (int mi = 0; mi < 4; mi++) {
    float bv = bias[m0 + mg * 4 + mi];
    float4 o0, o1;
    o0.x = acc[mi][0] + bv; o0.y = acc[mi][1] + bv;
    o0.z = acc[mi][2] + bv; o0.w = acc[mi][3] + bv;
    o1.x = acc[mi][4] + bv; o1.y = acc[mi][5] + bv;
    o1.z = acc[mi][6] + bv; o1.w = acc[mi][7] + bv;
    float* orow = &Ob[(size_t)(m0 + mg * 4 + mi) * S_ + n0];
    *(float4*)&orow[ng * 4] = o0;
    *(float4*)&orow[64 + ng * 4] = o1;
  }
}

// ---------------------------------------------------------------------------
// Row attention: per (b,n,h): S[i,w] = SCALE*sum_d rq[d,i,w]*rk[d,h,w],
// softmax over i (columns), store transposed bf16: arT[b,n,h][w][i].
// Grid (hg=8, n=8, b=4), block 256, 6 h per block. rq staged bf16 in LDS.
// ---------------------------------------------------------------------------
__global__ __launch_bounds__(256) void row_attn_kernel(
    const float* __restrict__ rcv, u16* __restrict__ arT)
{
  __shared__ u16  rq[16 * 2304];     // [d][i*48+w]  73728 B
  __shared__ float rk[16 * 48];
  __shared__ float Sm[48 * 49];      // [i][w] padded
  __shared__ float cmax[48], crs[48];
  const int hg = blockIdx.x, n = blockIdx.y, b = blockIdx.z;
  const float* base = rcv + ((size_t)b * 768 + n * 96) * S_;  // rq; rk at +16*S_
  const int tid = threadIdx.x;

  for (int id = tid; id < 9216; id += 256) {     // 16*2304/4 float4s
    float4 v = *(const float4*)&base[id * 4];
    short4 s;
    s.x = (short)f2bf(v.x); s.y = (short)f2bf(v.y);
    s.z = (short)f2bf(v.z); s.w = (short)f2bf(v.w);
    *(short4*)&rq[id * 4] = s;
  }

  for (int hh = 0; hh < 6; hh++) {
    int h = hg * 6 + hh;
    for (int id = tid; id < 768; id += 256) {
      int d = id / 48, w = id % 48;
      rk[id] = base[(size_t)(16 + d) * S_ + h * 48 + w];
    }
    __syncthreads();
    for (int id = tid; id < 2304; id += 256) {
      int i = id / 48, w = id % 48;
      float s = 0.f;
#pragma unroll
      for (int d = 0; d < 16; d++)
        s += bf2f(rq[d * 2304 + i * 48 + w]) * rk[d * 48 + w];
      Sm[i * 49 + w] = s * 0.25f;
    }
    __syncthreads();
    if (tid < 48) {
      int w = tid;
      float m = -1e30f;
      for (int i = 0; i < 48; i++) m = fmaxf(m, Sm[i * 49 + w]);
      float s = 0.f;
      for (int i = 0; i < 48; i++) s += __expf(Sm[i * 49 + w] - m);
      cmax[w] = m; crs[w] = 1.0f / s;
    }
    __syncthreads();
    u16* dst = arT + ((size_t)(b * 8 + n) * 48 + h) * 2304;
    for (int id = tid; id < 2304; id += 256) {
      int w = id / 48, i = id % 48;
      float p = __expf(Sm[i * 49 + w] - cmax[w]) * crs[w];
      dst[id] = f2bf(p);                  // layout [w][i]
    }
    __syncthreads();
  }
}

// ---------------------------------------------------------------------------
// Col attention: per (b,n,h): T[w,j] = SCALE*sum_d ck[d,h,w]*cq[d,h,j],
// softmax over j (rows), store bf16: awT[b,n,h][w][j].
// ---------------------------------------------------------------------------
__global__ __launch_bounds__(256) void col_attn_kernel(
    const float* __restrict__ rcv, u16* __restrict__ awT)
{
  __shared__ float cq[16 * 48], ck[16 * 48];
  __shared__ float Tm[48 * 49];
  __shared__ float rmax[48], rrs[48];
  const int hg = blockIdx.x, n = blockIdx.y, b = blockIdx.z;
  const float* base = rcv + ((size_t)b * 768 + n * 96 + 32) * S_; // cq; ck at +16*S_
  const int tid = threadIdx.x;

  for (int hh = 0; hh < 6; hh++) {
    int h = hg * 6 + hh;
    for (int id = tid; id < 768; id += 256) {
      int d = id / 48, j = id % 48;
      cq[id] = base[(size_t)d * S_ + h * 48 + j];
      ck[id] = base[(size_t)(16 + d) * S_ + h * 48 + j];
    }
    __syncthreads();
    for (int id = tid; id < 2304; id += 256) {
      int w = id / 48, j = id % 48;
      float t = 0.f;
#pragma unroll
      for (int d = 0; d < 16; d++)
        t += ck[d * 48 + w] * cq[d * 48 + j];
      Tm[w * 49 + j] = t * 0.25f;
    }
    __syncthreads();
    if (tid < 48) {
      int w = tid;
      float m = -1e30f;
      for (int j = 0; j < 48; j++) m = fmaxf(m, Tm[w * 49 + j]);
      float s = 0.f;
      for (int j = 0; j < 48; j++) s += __expf(Tm[w * 49 + j] - m);
      rmax[w] = m; rrs[w] = 1.0f / s;
    }
    __syncthreads();
    u16* dst = awT + ((size_t)(b * 8 + n) * 48 + h) * 2304;
    for (int id = tid; id < 2304; id += 256) {
      int w = id / 48, j = id % 48;
      float p = __expf(Tm[w * 49 + j] - rmax[w]) * rrs[w];
      dst[id] = f2bf(p);                  // layout [w][j]
    }
    __syncthreads();
  }
}

// ---------------------------------------------------------------------------
// Main contraction + PE conv. Grid (dchunk=8, n=8, b=4), 256 thr = 4 waves.
// Per block: 4 d-planes of v resident in LDS bf16 (rows = dloc*48+i, K pad 72).
// Loop h: P[(d,i),w] = sum_j v[d,i,j]*aw[j;h,w] via MFMA 16x16x32 bf16
// (wave = dloc, 3 mtiles x 3 ntiles x 2 ksteps), epilogue:
// y[d,h,w] = sum_i arT[w][i] * P[(d,i),w]  (in-register + shfl_xor 16/32).
// After loop: add depthwise 3x3 PE conv from resident v, write y once.
// ---------------------------------------------------------------------------
__global__ __launch_bounds__(256) void attn_main_kernel(
    const float* __restrict__ rcv, const u16* __restrict__ arT,
    const u16* __restrict__ awT, const float* __restrict__ pe_w,
    const float* __restrict__ pe_b, float* __restrict__ y)
{
  __shared__ u16 vA[192 * 72];     // 27648 B  [(dloc,i)][j pad]
  __shared__ u16 awB[48 * 72];     //  6912 B  [w][j pad]
  __shared__ u16 arB[48 * 72];     //  6912 B  [w][i pad]
  __shared__ float yacc[4 * 48 * 48]; // 36864 B [dloc][h][w]
  const int dchunk = blockIdx.x, n = blockIdx.y, b = blockIdx.z;
  const int tid = threadIdx.x;
  const int wave = tid >> 6, lane = tid & 63;
  const int lr = lane & 15, lg = lane >> 4;

  for (int id = tid; id < 192 * 72; id += 256) vA[id] = 0;
  for (int id = tid; id < 48 * 72; id += 256) { awB[id] = 0; arB[id] = 0; }
  __syncthreads();

  const float* vbase = rcv + ((size_t)b * 768 + n * 96 + 64 + dchunk * 4) * S_;
  for (int id = tid; id < 2304; id += 256) {   // 4 planes * 576 float4
    int dl = id / 576, rem = id % 576;
    int i = rem / 12, j4 = (rem % 12) * 4;
    float4 v = *(const float4*)&vbase[(size_t)dl * S_ + i * 48 + j4];
    short4 s;
    s.x = (short)f2bf(v.x); s.y = (short)f2bf(v.y);
    s.z = (short)f2bf(v.z); s.w = (short)f2bf(v.w);
    *(short4*)&vA[(dl * 48 + i) * 72 + j4] = s;
  }
  __syncthreads();

  const size_t bnh0 = ((size_t)(b * 8 + n) * 48) * 2304;
  for (int h = 0; h < 48; h++) {
    const u16* awg = awT + bnh0 + (size_t)h * 2304;
    const u16* arg = arT + bnh0 + (size_t)h * 2304;
    for (int id = tid; id < 576; id += 256) {
      int w = id / 12, j4 = (id % 12) * 4;
      *(short4*)&awB[w * 72 + j4] = *(const short4*)&awg[id * 4];
      *(short4*)&arB[w * 72 + j4] = *(const short4*)&arg[id * 4];
    }
    __syncthreads();

    f32x4 zero = {0.f, 0.f, 0.f, 0.f};
    f32x4 acc[3][3];
#pragma unroll
    for (int mt = 0; mt < 3; mt++)
#pragma unroll
      for (int nt = 0; nt < 3; nt++) acc[mt][nt] = zero;

#pragma unroll
    for (int ks = 0; ks < 2; ks++) {
      bf16x8 af[3], bfr[3];
#pragma unroll
      for (int mt = 0; mt < 3; mt++)
        af[mt] = *(const bf16x8*)&vA[(wave * 48 + mt * 16 + lr) * 72 + ks * 32 + lg * 8];
#pragma unroll
      for (int nt = 0; nt < 3; nt++)
        bfr[nt] = *(const bf16x8*)&awB[(nt * 16 + lr) * 72 + ks * 32 + lg * 8];
#pragma unroll
      for (int mt = 0; mt < 3; mt++)
#pragma unroll
        for (int nt = 0; nt < 3; nt++)
          acc[mt][nt] = __builtin_amdgcn_mfma_f32_16x16x32_bf16(
              af[mt], bfr[nt], acc[mt][nt], 0, 0, 0);
    }

#pragma unroll
    for (int nt = 0; nt < 3; nt++) {
      int wc = nt * 16 + lr;
      float p = 0.f;
#pragma unroll
      for (int mt = 0; mt < 3; mt++) {
        short4 s = *(const short4*)&arB[wc * 72 + mt * 16 + lg * 4];
        p += bf2f((u16)s.x) * acc[mt][nt][0] + bf2f((u16)s.y) * acc[mt][nt][1]
           + bf2f((u16)s.z) * acc[mt][nt][2] + bf2f((u16)s.w) * acc[mt][nt][3];
      }
      p += __shfl_xor(p, 16);
      p += __shfl_xor(p, 32);
      if (lane < 16) yacc[wave * 2304 + h * 48 + wc] = p;
    }
    __syncthreads();
  }

  // PE depthwise 3x3 from resident v + single global write of y
  const int c = n * 32 + dchunk * 4 + wave;
  float pw[9];
#pragma unroll
  for (int t = 0; t < 9; t++) pw[t] = pe_w[c * 9 + t];
  const float pb = pe_b[c];
  float* yg = y + ((size_t)b * 256 + c) * S_;
  for (int p = 0; p < 36; p++) {
    int pos = lane + p * 64;
    int hh = pos / 48, ww = pos % 48;
    float a = yacc[wave * 2304 + pos] + pb;
#pragma unroll
    for (int kh = -1; kh <= 1; kh++) {
      int ih = hh + kh;
      if (ih < 0 || ih > 47) continue;
#pragma unroll
      for (int kw = -1; kw <= 1; kw++) {
        int jw = ww + kw;
        if (jw < 0 || jw > 47) continue;
        a += pw[(kh + 1) * 3 + (kw + 1)] * bf2f(vA[(wave * 48 + ih) * 72 + jw]);
      }
    }
    yg[pos] = a;
  }
}

// ---------------------------------------------------------------------------
extern "C" void kernel_launch(void* const* d_in, const int* in_sizes, int n_in,
                              void* d_out, int out_size, void* d_ws, size_t ws_size,
                              hipStream_t stream) {
  const float* x      = (const float*)d_in[0];
  const float* rcv_w  = (const float*)d_in[1];
  const float* rcv_b  = (const float*)d_in[2];
  const float* pe_w   = (const float*)d_in[3];
  const float* pe_b   = (const float*)d_in[4];
  const float* proj_w = (const float*)d_in[5];
  const float* proj_b = (const float*)d_in[6];
  float* out = (float*)d_out;

  char* ws = (char*)d_ws;
  float* rcv = (float*)ws;                                // 768*2304*4 floats = 28,311,552 B
  u16*   arT = (u16*)(ws + 28311552);                     // 3,538,944 u16 = 7,077,888 B
  u16*   awT = arT + 3538944;                             // 7,077,888 B
  float* y   = (float*)(ws + 28311552 + 14155776);        // 9,437,184 B  (total ~51.9 MB)

  gemm1x1_kernel<<<dim3(18, 12, 4), 256, 0, stream>>>(rcv_w, rcv_b, x, rcv, 768);
  row_attn_kernel<<<dim3(8, 8, 4), 256, 0, stream>>>(rcv, arT);
  col_attn_kernel<<<dim3(8, 8, 4), 256, 0, stream>>>(rcv, awT);
  attn_main_kernel<<<dim3(8, 8, 4), 256, 0, stream>>>(rcv, arT, awT, pe_w, pe_b, y);
  gemm1x1_kernel<<<dim3(18, 4, 4), 256, 0, stream>>>(proj_w, proj_b, y, out, 256);
}

// Round 3
// 211.798 us; speedup vs baseline: 1.1973x; 1.1973x over previous
//
#include <hip/hip_runtime.h>

#define S_ 2304   // 48*48

typedef unsigned short u16;
typedef __attribute__((ext_vector_type(8))) short bf16x8;
typedef __attribute__((ext_vector_type(4))) float f32x4;

static __device__ __forceinline__ u16 f2bf(float x) {
  union { float f; unsigned u; } v; v.f = x;
  unsigned r = v.u + 0x7FFFu + ((v.u >> 16) & 1u);
  return (u16)(r >> 16);
}
static __device__ __forceinline__ float bf2f(u16 h) {
  union { unsigned u; float f; } v; v.u = ((unsigned)h) << 16; return v.f;
}

// ---------------------------------------------------------------------------
// GEMM (1x1 conv): Out[b][m][s] = sum_k Wm[m][k] * X[b][k][s] + bias[m]
// K fixed at 256. Tile 64(m) x 128(n), 256 threads, 4x8 micro-tile.
// ---------------------------------------------------------------------------
__global__ __launch_bounds__(256) void gemm1x1_kernel(
    const float* __restrict__ Wm, const float* __restrict__ bias,
    const float* __restrict__ X, float* __restrict__ Out, int M)
{
  __shared__ float wT[32][68];    // [k][m], padded
  __shared__ float xT[32][136];   // [k][n], padded
  const int b  = blockIdx.z;
  const int m0 = blockIdx.y * 64;
  const int n0 = blockIdx.x * 128;
  const float* Xb = X + (size_t)b * 256 * S_;
  float* Ob = Out + (size_t)b * M * S_;
  const int tid = threadIdx.x;
  const int mg = tid >> 4, ng = tid & 15;
  float acc[4][8];
#pragma unroll
  for (int i = 0; i < 4; i++)
#pragma unroll
    for (int j = 0; j < 8; j++) acc[i][j] = 0.f;

  for (int k0 = 0; k0 < 256; k0 += 32) {
#pragma unroll
    for (int rep = 0; rep < 2; rep++) {
      int id = tid + rep * 256;
      int row = id >> 3, cg = (id & 7) * 4;
      float4 w4 = *(const float4*)&Wm[(size_t)(m0 + row) * 256 + k0 + cg];
      wT[cg + 0][row] = w4.x; wT[cg + 1][row] = w4.y;
      wT[cg + 2][row] = w4.z; wT[cg + 3][row] = w4.w;
    }
#pragma unroll
    for (int rep = 0; rep < 4; rep++) {
      int id = tid + rep * 256;
      int row = id >> 5, cg = (id & 31) * 4;
      *(float4*)&xT[row][cg] = *(const float4*)&Xb[(size_t)(k0 + row) * S_ + n0 + cg];
    }
    __syncthreads();
#pragma unroll
    for (int k = 0; k < 32; k++) {
      float4 a4 = *(float4*)&wT[k][mg * 4];
      float4 x0 = *(float4*)&xT[k][ng * 4];
      float4 x1 = *(float4*)&xT[k][64 + ng * 4];
      float av[4] = {a4.x, a4.y, a4.z, a4.w};
      float xv[8] = {x0.x, x0.y, x0.z, x0.w, x1.x, x1.y, x1.z, x1.w};
#pragma unroll
      for (int mi = 0; mi < 4; mi++)
#pragma unroll
        for (int ni = 0; ni < 8; ni++) acc[mi][ni] += av[mi] * xv[ni];
    }
    __syncthreads();
  }
#pragma unroll
  for (int mi = 0; mi < 4; mi++) {
    float bv = bias[m0 + mg * 4 + mi];
    float4 o0, o1;
    o0.x = acc[mi][0] + bv; o0.y = acc[mi][1] + bv;
    o0.z = acc[mi][2] + bv; o0.w = acc[mi][3] + bv;
    o1.x = acc[mi][4] + bv; o1.y = acc[mi][5] + bv;
    o1.z = acc[mi][6] + bv; o1.w = acc[mi][7] + bv;
    float* orow = &Ob[(size_t)(m0 + mg * 4 + mi) * S_ + n0];
    *(float4*)&orow[ng * 4] = o0;
    *(float4*)&orow[64 + ng * 4] = o1;
  }
}

// ---------------------------------------------------------------------------
// Row attention: per (b,n,h): S[i,w] = SCALE*sum_d rq[d,i,w]*rk[d,h,w],
// softmax over i (columns), store transposed bf16: arT[b,n,h][w][i].
// ---------------------------------------------------------------------------
__global__ __launch_bounds__(256) void row_attn_kernel(
    const float* __restrict__ rcv, u16* __restrict__ arT)
{
  __shared__ u16  rq[16 * 2304];     // [d][i*48+w]  73728 B
  __shared__ float rk[16 * 48];
  __shared__ float Sm[48 * 49];      // [i][w] padded
  __shared__ float cmax[48], crs[48];
  const int hg = blockIdx.x, n = blockIdx.y, b = blockIdx.z;
  const float* base = rcv + ((size_t)b * 768 + n * 96) * S_;  // rq; rk at +16*S_
  const int tid = threadIdx.x;

  for (int id = tid; id < 9216; id += 256) {     // 16*2304/4 float4s
    float4 v = *(const float4*)&base[id * 4];
    short4 s;
    s.x = (short)f2bf(v.x); s.y = (short)f2bf(v.y);
    s.z = (short)f2bf(v.z); s.w = (short)f2bf(v.w);
    *(short4*)&rq[id * 4] = s;
  }

  for (int hh = 0; hh < 6; hh++) {
    int h = hg * 6 + hh;
    for (int id = tid; id < 768; id += 256) {
      int d = id / 48, w = id % 48;
      rk[id] = base[(size_t)(16 + d) * S_ + h * 48 + w];
    }
    __syncthreads();
    for (int id = tid; id < 2304; id += 256) {
      int i = id / 48, w = id % 48;
      float s = 0.f;
#pragma unroll
      for (int d = 0; d < 16; d++)
        s += bf2f(rq[d * 2304 + i * 48 + w]) * rk[d * 48 + w];
      Sm[i * 49 + w] = s * 0.25f;
    }
    __syncthreads();
    if (tid < 48) {
      int w = tid;
      float m = -1e30f;
      for (int i = 0; i < 48; i++) m = fmaxf(m, Sm[i * 49 + w]);
      float s = 0.f;
      for (int i = 0; i < 48; i++) s += __expf(Sm[i * 49 + w] - m);
      cmax[w] = m; crs[w] = 1.0f / s;
    }
    __syncthreads();
    u16* dst = arT + ((size_t)(b * 8 + n) * 48 + h) * 2304;
    for (int id = tid; id < 2304; id += 256) {
      int w = id / 48, i = id % 48;
      float p = __expf(Sm[i * 49 + w] - cmax[w]) * crs[w];
      dst[id] = f2bf(p);                  // layout [w][i]
    }
    __syncthreads();
  }
}

// ---------------------------------------------------------------------------
// Col attention: per (b,n,h): T[w,j] = SCALE*sum_d ck[d,h,w]*cq[d,h,j],
// softmax over j (rows), store bf16: awT[b,n,h][w][j].
// ---------------------------------------------------------------------------
__global__ __launch_bounds__(256) void col_attn_kernel(
    const float* __restrict__ rcv, u16* __restrict__ awT)
{
  __shared__ float cq[16 * 48], ck[16 * 48];
  __shared__ float Tm[48 * 49];
  __shared__ float rmax[48], rrs[48];
  const int hg = blockIdx.x, n = blockIdx.y, b = blockIdx.z;
  const float* base = rcv + ((size_t)b * 768 + n * 96 + 32) * S_; // cq; ck at +16*S_
  const int tid = threadIdx.x;

  for (int hh = 0; hh < 6; hh++) {
    int h = hg * 6 + hh;
    for (int id = tid; id < 768; id += 256) {
      int d = id / 48, j = id % 48;
      cq[id] = base[(size_t)d * S_ + h * 48 + j];
      ck[id] = base[(size_t)(16 + d) * S_ + h * 48 + j];
    }
    __syncthreads();
    for (int id = tid; id < 2304; id += 256) {
      int w = id / 48, j = id % 48;
      float t = 0.f;
#pragma unroll
      for (int d = 0; d < 16; d++)
        t += ck[d * 48 + w] * cq[d * 48 + j];
      Tm[w * 49 + j] = t * 0.25f;
    }
    __syncthreads();
    if (tid < 48) {
      int w = tid;
      float m = -1e30f;
      for (int j = 0; j < 48; j++) m = fmaxf(m, Tm[w * 49 + j]);
      float s = 0.f;
      for (int j = 0; j < 48; j++) s += __expf(Tm[w * 49 + j] - m);
      rmax[w] = m; rrs[w] = 1.0f / s;
    }
    __syncthreads();
    u16* dst = awT + ((size_t)(b * 8 + n) * 48 + h) * 2304;
    for (int id = tid; id < 2304; id += 256) {
      int w = id / 48, j = id % 48;
      float p = __expf(Tm[w * 49 + j] - rmax[w]) * rrs[w];
      dst[id] = f2bf(p);                  // layout [w][j]
    }
    __syncthreads();
  }
}

// ---------------------------------------------------------------------------
// Main contraction + PE conv. Grid (dchunk=8, n=8, b*hc=16), 256 thr = 4 waves.
// Each block handles 12 h values (hc selects which 12) -> 1024 blocks,
// LDS 50.7 KB -> 3 blocks/CU resident (12 waves/CU).
// ---------------------------------------------------------------------------
__global__ __launch_bounds__(256) void attn_main_kernel(
    const float* __restrict__ rcv, const u16* __restrict__ arT,
    const u16* __restrict__ awT, const float* __restrict__ pe_w,
    const float* __restrict__ pe_b, float* __restrict__ y)
{
  __shared__ u16 vA[192 * 72];        // 27648 B  [(dloc,i)][j pad]
  __shared__ u16 awB[48 * 72];        //  6912 B  [w][j pad]
  __shared__ u16 arB[48 * 72];        //  6912 B  [w][i pad]
  __shared__ float yacc[4 * 12 * 48]; //  9216 B  [dloc][hh][w]
  const int dchunk = blockIdx.x, n = blockIdx.y;
  const int b = blockIdx.z >> 2, hc = blockIdx.z & 3;
  const int h0 = hc * 12;
  const int tid = threadIdx.x;
  const int wave = tid >> 6, lane = tid & 63;
  const int lr = lane & 15, lg = lane >> 4;

  for (int id = tid; id < 192 * 72; id += 256) vA[id] = 0;
  for (int id = tid; id < 48 * 72; id += 256) { awB[id] = 0; arB[id] = 0; }
  __syncthreads();

  const float* vbase = rcv + ((size_t)b * 768 + n * 96 + 64 + dchunk * 4) * S_;
  for (int id = tid; id < 2304; id += 256) {   // 4 planes * 576 float4
    int dl = id / 576, rem = id % 576;
    int i = rem / 12, j4 = (rem % 12) * 4;
    float4 v = *(const float4*)&vbase[(size_t)dl * S_ + i * 48 + j4];
    short4 s;
    s.x = (short)f2bf(v.x); s.y = (short)f2bf(v.y);
    s.z = (short)f2bf(v.z); s.w = (short)f2bf(v.w);
    *(short4*)&vA[(dl * 48 + i) * 72 + j4] = s;
  }
  __syncthreads();

  const size_t bnh0 = ((size_t)(b * 8 + n) * 48) * 2304;
  for (int hh = 0; hh < 12; hh++) {
    int h = h0 + hh;
    const u16* awg = awT + bnh0 + (size_t)h * 2304;
    const u16* arg = arT + bnh0 + (size_t)h * 2304;
    for (int id = tid; id < 576; id += 256) {
      int w = id / 12, j4 = (id % 12) * 4;
      *(short4*)&awB[w * 72 + j4] = *(const short4*)&awg[id * 4];
      *(short4*)&arB[w * 72 + j4] = *(const short4*)&arg[id * 4];
    }
    __syncthreads();

    f32x4 zero = {0.f, 0.f, 0.f, 0.f};
    f32x4 acc[3][3];
#pragma unroll
    for (int mt = 0; mt < 3; mt++)
#pragma unroll
      for (int nt = 0; nt < 3; nt++) acc[mt][nt] = zero;

#pragma unroll
    for (int ks = 0; ks < 2; ks++) {
      bf16x8 af[3], bfr[3];
#pragma unroll
      for (int mt = 0; mt < 3; mt++)
        af[mt] = *(const bf16x8*)&vA[(wave * 48 + mt * 16 + lr) * 72 + ks * 32 + lg * 8];
#pragma unroll
      for (int nt = 0; nt < 3; nt++)
        bfr[nt] = *(const bf16x8*)&awB[(nt * 16 + lr) * 72 + ks * 32 + lg * 8];
#pragma unroll
      for (int mt = 0; mt < 3; mt++)
#pragma unroll
        for (int nt = 0; nt < 3; nt++)
          acc[mt][nt] = __builtin_amdgcn_mfma_f32_16x16x32_bf16(
              af[mt], bfr[nt], acc[mt][nt], 0, 0, 0);
    }

#pragma unroll
    for (int nt = 0; nt < 3; nt++) {
      int wc = nt * 16 + lr;
      float p = 0.f;
#pragma unroll
      for (int mt = 0; mt < 3; mt++) {
        short4 s = *(const short4*)&arB[wc * 72 + mt * 16 + lg * 4];
        p += bf2f((u16)s.x) * acc[mt][nt][0] + bf2f((u16)s.y) * acc[mt][nt][1]
           + bf2f((u16)s.z) * acc[mt][nt][2] + bf2f((u16)s.w) * acc[mt][nt][3];
      }
      p += __shfl_xor(p, 16);
      p += __shfl_xor(p, 32);
      if (lane < 16) yacc[wave * 576 + hh * 48 + wc] = p;
    }
    __syncthreads();
  }

  // PE depthwise 3x3 from resident v + single global write of y (12 h rows)
  const int c = n * 32 + dchunk * 4 + wave;
  float pw[9];
#pragma unroll
  for (int t = 0; t < 9; t++) pw[t] = pe_w[c * 9 + t];
  const float pb = pe_b[c];
  float* yg = y + ((size_t)b * 256 + c) * S_;
  for (int p = 0; p < 9; p++) {
    int pos = lane + p * 64;              // 0..575 within this h-chunk
    int hh = pos / 48, ww = pos % 48;
    int habs = h0 + hh;
    float a = yacc[wave * 576 + pos] + pb;
#pragma unroll
    for (int kh = -1; kh <= 1; kh++) {
      int ih = habs + kh;
      if (ih < 0 || ih > 47) continue;
#pragma unroll
      for (int kw = -1; kw <= 1; kw++) {
        int jw = ww + kw;
        if (jw < 0 || jw > 47) continue;
        a += pw[(kh + 1) * 3 + (kw + 1)] * bf2f(vA[(wave * 48 + ih) * 72 + jw]);
      }
    }
    yg[habs * 48 + ww] = a;
  }
}

// ---------------------------------------------------------------------------
extern "C" void kernel_launch(void* const* d_in, const int* in_sizes, int n_in,
                              void* d_out, int out_size, void* d_ws, size_t ws_size,
                              hipStream_t stream) {
  const float* x      = (const float*)d_in[0];
  const float* rcv_w  = (const float*)d_in[1];
  const float* rcv_b  = (const float*)d_in[2];
  const float* pe_w   = (const float*)d_in[3];
  const float* pe_b   = (const float*)d_in[4];
  const float* proj_w = (const float*)d_in[5];
  const float* proj_b = (const float*)d_in[6];
  float* out = (float*)d_out;

  char* ws = (char*)d_ws;
  float* rcv = (float*)ws;                                // 28,311,552 B
  u16*   arT = (u16*)(ws + 28311552);                     // 7,077,888 B
  u16*   awT = arT + 3538944;                             // 7,077,888 B
  float* y   = (float*)(ws + 28311552 + 14155776);        // 9,437,184 B

  gemm1x1_kernel<<<dim3(18, 12, 4), 256, 0, stream>>>(rcv_w, rcv_b, x, rcv, 768);
  row_attn_kernel<<<dim3(8, 8, 4), 256, 0, stream>>>(rcv, arT);
  col_attn_kernel<<<dim3(8, 8, 4), 256, 0, stream>>>(rcv, awT);
  attn_main_kernel<<<dim3(8, 8, 16), 256, 0, stream>>>(rcv, arT, awT, pe_w, pe_b, y);
  gemm1x1_kernel<<<dim3(18, 4, 4), 256, 0, stream>>>(proj_w, proj_b, y, out, 256);
}

// Round 4
// 182.858 us; speedup vs baseline: 1.3868x; 1.1583x over previous
//
#include <hip/hip_runtime.h>

#define S_ 2304   // 48*48

typedef unsigned short u16;
typedef __attribute__((ext_vector_type(8))) short bf16x8;
typedef __attribute__((ext_vector_type(4))) float f32x4;

static __device__ __forceinline__ u16 f2bf(float x) {
  union { float f; unsigned u; } v; v.f = x;
  unsigned r = v.u + 0x7FFFu + ((v.u >> 16) & 1u);
  return (u16)(r >> 16);
}
static __device__ __forceinline__ float bf2f(u16 h) {
  union { unsigned u; float f; } v; v.u = ((unsigned)h) << 16; return v.f;
}

// ---------------------------------------------------------------------------
// GEMM (1x1 conv): Out[b][m][s] = sum_k Wm[m][k] * X[b][k][s] + bias[m]
// K fixed at 256. Tile 64(m) x 128(n), 256 threads, 4x8 micro-tile.
// ---------------------------------------------------------------------------
__global__ __launch_bounds__(256) void gemm1x1_kernel(
    const float* __restrict__ Wm, const float* __restrict__ bias,
    const float* __restrict__ X, float* __restrict__ Out, int M)
{
  __shared__ float wT[32][68];    // [k][m], padded
  __shared__ float xT[32][136];   // [k][n], padded
  const int b  = blockIdx.z;
  const int m0 = blockIdx.y * 64;
  const int n0 = blockIdx.x * 128;
  const float* Xb = X + (size_t)b * 256 * S_;
  float* Ob = Out + (size_t)b * M * S_;
  const int tid = threadIdx.x;
  const int mg = tid >> 4, ng = tid & 15;
  float acc[4][8];
#pragma unroll
  for (int i = 0; i < 4; i++)
#pragma unroll
    for (int j = 0; j < 8; j++) acc[i][j] = 0.f;

  for (int k0 = 0; k0 < 256; k0 += 32) {
#pragma unroll
    for (int rep = 0; rep < 2; rep++) {
      int id = tid + rep * 256;
      int row = id >> 3, cg = (id & 7) * 4;
      float4 w4 = *(const float4*)&Wm[(size_t)(m0 + row) * 256 + k0 + cg];
      wT[cg + 0][row] = w4.x; wT[cg + 1][row] = w4.y;
      wT[cg + 2][row] = w4.z; wT[cg + 3][row] = w4.w;
    }
#pragma unroll
    for (int rep = 0; rep < 4; rep++) {
      int id = tid + rep * 256;
      int row = id >> 5, cg = (id & 31) * 4;
      *(float4*)&xT[row][cg] = *(const float4*)&Xb[(size_t)(k0 + row) * S_ + n0 + cg];
    }
    __syncthreads();
#pragma unroll
    for (int k = 0; k < 32; k++) {
      float4 a4 = *(float4*)&wT[k][mg * 4];
      float4 x0 = *(float4*)&xT[k][ng * 4];
      float4 x1 = *(float4*)&xT[k][64 + ng * 4];
      float av[4] = {a4.x, a4.y, a4.z, a4.w};
      float xv[8] = {x0.x, x0.y, x0.z, x0.w, x1.x, x1.y, x1.z, x1.w};
#pragma unroll
      for (int mi = 0; mi < 4; mi++)
#pragma unroll
        for (int ni = 0; ni < 8; ni++) acc[mi][ni] += av[mi] * xv[ni];
    }
    __syncthreads();
  }
#pragma unroll
  for (int mi = 0; mi < 4; mi++) {
    float bv = bias[m0 + mg * 4 + mi];
    float4 o0, o1;
    o0.x = acc[mi][0] + bv; o0.y = acc[mi][1] + bv;
    o0.z = acc[mi][2] + bv; o0.w = acc[mi][3] + bv;
    o1.x = acc[mi][4] + bv; o1.y = acc[mi][5] + bv;
    o1.z = acc[mi][6] + bv; o1.w = acc[mi][7] + bv;
    float* orow = &Ob[(size_t)(m0 + mg * 4 + mi) * S_ + n0];
    *(float4*)&orow[ng * 4] = o0;
    *(float4*)&orow[64 + ng * 4] = o1;
  }
}

// ---------------------------------------------------------------------------
// Row attention: per (b,n,h): S[i,w] = SCALE*sum_d rq[d,i,w]*rk[d,h,w],
// softmax over i (columns), store transposed bf16: arT[b,n,h][w][i].
// ---------------------------------------------------------------------------
__global__ __launch_bounds__(256) void row_attn_kernel(
    const float* __restrict__ rcv, u16* __restrict__ arT)
{
  __shared__ u16  rq[16 * 2304];     // [d][i*48+w]  73728 B
  __shared__ float rk[16 * 48];
  __shared__ float Sm[48 * 49];      // [i][w] padded
  __shared__ float cmax[48], crs[48];
  const int hg = blockIdx.x, n = blockIdx.y, b = blockIdx.z;
  const float* base = rcv + ((size_t)b * 768 + n * 96) * S_;  // rq; rk at +16*S_
  const int tid = threadIdx.x;

  for (int id = tid; id < 9216; id += 256) {     // 16*2304/4 float4s
    float4 v = *(const float4*)&base[id * 4];
    short4 s;
    s.x = (short)f2bf(v.x); s.y = (short)f2bf(v.y);
    s.z = (short)f2bf(v.z); s.w = (short)f2bf(v.w);
    *(short4*)&rq[id * 4] = s;
  }

  for (int hh = 0; hh < 6; hh++) {
    int h = hg * 6 + hh;
    for (int id = tid; id < 768; id += 256) {
      int d = id / 48, w = id % 48;
      rk[id] = base[(size_t)(16 + d) * S_ + h * 48 + w];
    }
    __syncthreads();
    for (int id = tid; id < 2304; id += 256) {
      int i = id / 48, w = id % 48;
      float s = 0.f;
#pragma unroll
      for (int d = 0; d < 16; d++)
        s += bf2f(rq[d * 2304 + i * 48 + w]) * rk[d * 48 + w];
      Sm[i * 49 + w] = s * 0.25f;
    }
    __syncthreads();
    if (tid < 48) {
      int w = tid;
      float m = -1e30f;
      for (int i = 0; i < 48; i++) m = fmaxf(m, Sm[i * 49 + w]);
      float s = 0.f;
      for (int i = 0; i < 48; i++) s += __expf(Sm[i * 49 + w] - m);
      cmax[w] = m; crs[w] = 1.0f / s;
    }
    __syncthreads();
    u16* dst = arT + ((size_t)(b * 8 + n) * 48 + h) * 2304;
    for (int id = tid; id < 2304; id += 256) {
      int w = id / 48, i = id % 48;
      float p = __expf(Sm[i * 49 + w] - cmax[w]) * crs[w];
      dst[id] = f2bf(p);                  // layout [w][i]
    }
    __syncthreads();
  }
}

// ---------------------------------------------------------------------------
// Col attention: per (b,n,h): T[w,j] = SCALE*sum_d ck[d,h,w]*cq[d,h,j],
// softmax over j (rows), store bf16: awT[b,n,h][w][j].
// ---------------------------------------------------------------------------
__global__ __launch_bounds__(256) void col_attn_kernel(
    const float* __restrict__ rcv, u16* __restrict__ awT)
{
  __shared__ float cq[16 * 48], ck[16 * 48];
  __shared__ float Tm[48 * 49];
  __shared__ float rmax[48], rrs[48];
  const int hg = blockIdx.x, n = blockIdx.y, b = blockIdx.z;
  const float* base = rcv + ((size_t)b * 768 + n * 96 + 32) * S_; // cq; ck at +16*S_
  const int tid = threadIdx.x;

  for (int hh = 0; hh < 6; hh++) {
    int h = hg * 6 + hh;
    for (int id = tid; id < 768; id += 256) {
      int d = id / 48, j = id % 48;
      cq[id] = base[(size_t)d * S_ + h * 48 + j];
      ck[id] = base[(size_t)(16 + d) * S_ + h * 48 + j];
    }
    __syncthreads();
    for (int id = tid; id < 2304; id += 256) {
      int w = id / 48, j = id % 48;
      float t = 0.f;
#pragma unroll
      for (int d = 0; d < 16; d++)
        t += ck[d * 48 + w] * cq[d * 48 + j];
      Tm[w * 49 + j] = t * 0.25f;
    }
    __syncthreads();
    if (tid < 48) {
      int w = tid;
      float m = -1e30f;
      for (int j = 0; j < 48; j++) m = fmaxf(m, Tm[w * 49 + j]);
      float s = 0.f;
      for (int j = 0; j < 48; j++) s += __expf(Tm[w * 49 + j] - m);
      rmax[w] = m; rrs[w] = 1.0f / s;
    }
    __syncthreads();
    u16* dst = awT + ((size_t)(b * 8 + n) * 48 + h) * 2304;
    for (int id = tid; id < 2304; id += 256) {
      int w = id / 48, j = id % 48;
      float p = __expf(Tm[w * 49 + j] - rmax[w]) * rrs[w];
      dst[id] = f2bf(p);                  // layout [w][j]
    }
    __syncthreads();
  }
}

// ---------------------------------------------------------------------------
// Main contraction + PE conv, wave-independent version.
// Grid 1024 blocks (1D, XCD-swizzled: n = id&7), 256 thr = 4 waves.
// wave = local d-plane dl; each wave handles 12 h values independently:
//   aw B-fragments + ar fragments loaded DIRECTLY global->reg (layout [w][j]
//   makes each lane's fragment a contiguous aligned 16B/8B chunk).
//   K=48 tail: B lanes with j>=48 zeroed (vA j-pad also zero).
// Only ONE barrier per block (after v staging). LDS = 27.6 KB -> whole grid
// co-resident (4 blocks/CU, 16 waves/CU).
// ---------------------------------------------------------------------------
__global__ __launch_bounds__(256) void attn_main_kernel(
    const float* __restrict__ rcv, const u16* __restrict__ arT,
    const u16* __restrict__ awT, const float* __restrict__ pe_w,
    const float* __restrict__ pe_b, float* __restrict__ y)
{
  __shared__ u16 vA[192 * 72];        // 27648 B  [(dloc,i)][j pad]
  const int id0 = blockIdx.x;
  const int n = id0 & 7;              // XCD swizzle: same n -> same XCD (rr assumption)
  const int rest = id0 >> 3;          // 0..127
  const int b = rest >> 5;            // 0..3
  const int inner = rest & 31;        // 0..31
  const int dchunk = inner >> 2;      // 0..7
  const int hc = inner & 3;           // 0..3
  const int h0 = hc * 12;
  const int tid = threadIdx.x;
  const int wave = tid >> 6, lane = tid & 63;
  const int lr = lane & 15, lg = lane >> 4;

  // zero only the j-pad columns (48..71); staging fills cols 0..47
  for (int id = tid; id < 192 * 24; id += 256) {
    int row = id / 24, col = 48 + id % 24;
    vA[row * 72 + col] = 0;
  }
  const float* vbase = rcv + ((size_t)b * 768 + n * 96 + 64 + dchunk * 4) * S_;
  for (int id = tid; id < 2304; id += 256) {   // 4 planes * 576 float4
    int dl = id / 576, rem = id % 576;
    int i = rem / 12, j4 = (rem % 12) * 4;
    float4 v = *(const float4*)&vbase[(size_t)dl * S_ + i * 48 + j4];
    short4 s;
    s.x = (short)f2bf(v.x); s.y = (short)f2bf(v.y);
    s.z = (short)f2bf(v.z); s.w = (short)f2bf(v.w);
    *(short4*)&vA[(dl * 48 + i) * 72 + j4] = s;
  }
  __syncthreads();   // the only barrier

  const size_t bnh0 = ((size_t)(b * 8 + n) * 48) * 2304;
  const int c = n * 32 + dchunk * 4 + wave;    // global channel of this wave's d-plane
  float pw[9];
#pragma unroll
  for (int t = 0; t < 9; t++) pw[t] = pe_w[c * 9 + t];
  const float pb = pe_b[c];
  float* yg = y + ((size_t)b * 256 + c) * S_;
  const int vrow0 = wave * 48;
  const bf16x8 zv = {0, 0, 0, 0, 0, 0, 0, 0};

  for (int hh = 0; hh < 12; hh++) {
    int h = h0 + hh;
    const u16* awg = awT + bnh0 + (size_t)h * 2304;  // [w][j], stride 48
    const u16* arg = arT + bnh0 + (size_t)h * 2304;  // [w][i], stride 48

    // B fragments direct from global: n=lr (w), k = lg*8+t
    bf16x8 bf0[3], bf1[3];
#pragma unroll
    for (int nt = 0; nt < 3; nt++) {
      int row = (nt * 16 + lr) * 48;
      bf0[nt] = *(const bf16x8*)&awg[row + lg * 8];            // j = 0..31
      bf1[nt] = (lg < 2) ? *(const bf16x8*)&awg[row + 32 + lg * 8]  // j = 32..47
                         : zv;                                 // j >= 48 -> 0
    }

    f32x4 acc[3][3];
#pragma unroll
    for (int mt = 0; mt < 3; mt++)
#pragma unroll
      for (int nt = 0; nt < 3; nt++) acc[mt][nt] = (f32x4){0.f, 0.f, 0.f, 0.f};

#pragma unroll
    for (int mt = 0; mt < 3; mt++) {
      bf16x8 a0 = *(const bf16x8*)&vA[(vrow0 + mt * 16 + lr) * 72 + lg * 8];
      bf16x8 a1 = *(const bf16x8*)&vA[(vrow0 + mt * 16 + lr) * 72 + 32 + lg * 8];
#pragma unroll
      for (int nt = 0; nt < 3; nt++) {
        acc[mt][nt] = __builtin_amdgcn_mfma_f32_16x16x32_bf16(a0, bf0[nt], acc[mt][nt], 0, 0, 0);
        acc[mt][nt] = __builtin_amdgcn_mfma_f32_16x16x32_bf16(a1, bf1[nt], acc[mt][nt], 0, 0, 0);
      }
    }

    // contract i with ar (direct global 8B reads), reduce over lane groups
    float pv[3];
#pragma unroll
    for (int nt = 0; nt < 3; nt++) {
      int wrow = (nt * 16 + lr) * 48;
      float p = 0.f;
#pragma unroll
      for (int mt = 0; mt < 3; mt++) {
        short4 s = *(const short4*)&arg[wrow + mt * 16 + lg * 4];
        p += bf2f((u16)s.x) * acc[mt][nt][0] + bf2f((u16)s.y) * acc[mt][nt][1]
           + bf2f((u16)s.z) * acc[mt][nt][2] + bf2f((u16)s.w) * acc[mt][nt][3];
      }
      p += __shfl_xor(p, 16);
      p += __shfl_xor(p, 32);
      pv[nt] = p;             // all lanes: value for w = nt*16 + lr
    }

    // lanes 0..47 write w=lane: PE depthwise 3x3 from resident v + store
    if (lane < 48) {
      float a = (lane < 16) ? pv[0] : (lane < 32 ? pv[1] : pv[2]);
      a += pb;
      int ww = lane;
#pragma unroll
      for (int kh = -1; kh <= 1; kh++) {
        int ih = h + kh;
        if (ih < 0 || ih > 47) continue;
#pragma unroll
        for (int kw = -1; kw <= 1; kw++) {
          int jw = ww + kw;
          if (jw < 0 || jw > 47) continue;
          a += pw[(kh + 1) * 3 + (kw + 1)] * bf2f(vA[(vrow0 + ih) * 72 + jw]);
        }
      }
      yg[h * 48 + ww] = a;
    }
  }
}

// ---------------------------------------------------------------------------
extern "C" void kernel_launch(void* const* d_in, const int* in_sizes, int n_in,
                              void* d_out, int out_size, void* d_ws, size_t ws_size,
                              hipStream_t stream) {
  const float* x      = (const float*)d_in[0];
  const float* rcv_w  = (const float*)d_in[1];
  const float* rcv_b  = (const float*)d_in[2];
  const float* pe_w   = (const float*)d_in[3];
  const float* pe_b   = (const float*)d_in[4];
  const float* proj_w = (const float*)d_in[5];
  const float* proj_b = (const float*)d_in[6];
  float* out = (float*)d_out;

  char* ws = (char*)d_ws;
  float* rcv = (float*)ws;                                // 28,311,552 B
  u16*   arT = (u16*)(ws + 28311552);                     // 7,077,888 B
  u16*   awT = arT + 3538944;                             // 7,077,888 B
  float* y   = (float*)(ws + 28311552 + 14155776);        // 9,437,184 B

  gemm1x1_kernel<<<dim3(18, 12, 4), 256, 0, stream>>>(rcv_w, rcv_b, x, rcv, 768);
  row_attn_kernel<<<dim3(8, 8, 4), 256, 0, stream>>>(rcv, arT);
  col_attn_kernel<<<dim3(8, 8, 4), 256, 0, stream>>>(rcv, awT);
  attn_main_kernel<<<dim3(1024), 256, 0, stream>>>(rcv, arT, awT, pe_w, pe_b, y);
  gemm1x1_kernel<<<dim3(18, 4, 4), 256, 0, stream>>>(proj_w, proj_b, y, out, 256);
}

// Round 5
// 164.129 us; speedup vs baseline: 1.5451x; 1.1141x over previous
//
#include <hip/hip_runtime.h>

#define S_ 2304   // 48*48

typedef unsigned short u16;
typedef __attribute__((ext_vector_type(8))) short bf16x8;
typedef __attribute__((ext_vector_type(4))) float f32x4;

static __device__ __forceinline__ u16 f2bf(float x) {
  union { float f; unsigned u; } v; v.f = x;
  unsigned r = v.u + 0x7FFFu + ((v.u >> 16) & 1u);
  return (u16)(r >> 16);
}
static __device__ __forceinline__ float bf2f(u16 h) {
  union { unsigned u; float f; } v; v.u = ((unsigned)h) << 16; return v.f;
}

// ---------------------------------------------------------------------------
// Weight split: fp32 -> bf16 hi + bf16 lo(residual). n multiple of 1024.
// ---------------------------------------------------------------------------
__global__ __launch_bounds__(256) void splitw_kernel(
    const float* __restrict__ w, u16* __restrict__ wh, u16* __restrict__ wl)
{
  int id = blockIdx.x * 256 + threadIdx.x;
  float4 v = ((const float4*)w)[id];
  short4 h, l;
  float f[4] = {v.x, v.y, v.z, v.w};
  u16 hh[4], ll[4];
#pragma unroll
  for (int q = 0; q < 4; q++) {
    hh[q] = f2bf(f[q]);
    ll[q] = f2bf(f[q] - bf2f(hh[q]));
  }
  h.x = hh[0]; h.y = hh[1]; h.z = hh[2]; h.w = hh[3];
  l.x = ll[0]; l.y = ll[1]; l.z = ll[2]; l.w = ll[3];
  ((short4*)wh)[id] = h;
  ((short4*)wl)[id] = l;
}

// ---------------------------------------------------------------------------
// Split-transpose: in[b][256][2304] fp32 -> outh/outl[b][2304][256] bf16 h/l.
// 64x64 tiles via LDS (u32-packed h|l). Grid (36, 4, 4b).
// ---------------------------------------------------------------------------
__global__ __launch_bounds__(256) void split_transpose_kernel(
    const float* __restrict__ in, u16* __restrict__ outh, u16* __restrict__ outl)
{
  __shared__ unsigned tile[64][65];
  const int s0 = blockIdx.x * 64, c0 = blockIdx.y * 64, b = blockIdx.z;
  const float* inb = in + (size_t)b * 256 * S_;
  u16* oh = outh + (size_t)b * S_ * 256;
  u16* ol = outl + (size_t)b * S_ * 256;
  const int tid = threadIdx.x;
#pragma unroll
  for (int it = 0; it < 4; it++) {
    int id = tid + it * 256;
    int c = id >> 4, s4 = (id & 15) * 4;
    float4 v = *(const float4*)&inb[(size_t)(c0 + c) * S_ + s0 + s4];
    float f[4] = {v.x, v.y, v.z, v.w};
#pragma unroll
    for (int q = 0; q < 4; q++) {
      u16 h = f2bf(f[q]);
      u16 l = f2bf(f[q] - bf2f(h));
      tile[s4 + q][c] = (unsigned)h | ((unsigned)l << 16);
    }
  }
  __syncthreads();
#pragma unroll
  for (int it = 0; it < 4; it++) {
    int id = tid + it * 256;
    int s = id >> 4, c4 = (id & 15) * 4;
    short4 h, l;
    unsigned p0 = tile[s][c4 + 0], p1 = tile[s][c4 + 1];
    unsigned p2 = tile[s][c4 + 2], p3 = tile[s][c4 + 3];
    h.x = (short)(p0 & 0xffff); h.y = (short)(p1 & 0xffff);
    h.z = (short)(p2 & 0xffff); h.w = (short)(p3 & 0xffff);
    l.x = (short)(p0 >> 16); l.y = (short)(p1 >> 16);
    l.z = (short)(p2 >> 16); l.w = (short)(p3 >> 16);
    *(short4*)&oh[(size_t)(s0 + s) * 256 + c0 + c4] = h;
    *(short4*)&ol[(size_t)(s0 + s) * 256 + c0 + c4] = l;
  }
}

// ---------------------------------------------------------------------------
// MFMA split-bf16 GEMM: Out[b][m][s] = sum_k W[m][k] X[b][k][s] + bias[m]
// 3-pass split: Wh*Xh + Wh*Xl + Wl*Xh (Wl*Xl ~1e-5, dropped).
// BM=64, BN=128, K=256 (8 ksteps of 32). 256 thr = 4 waves, wave tile 64x32
// (4 mt x 2 nt of 16x16x32). W-tiles dbuf in LDS (80B rows: 16B-aligned,
// 2-way-conflict-free). B-frags direct global->reg from XT[s][k] layout.
// 1D grid with XCD swizzle: all MB m-blocks of a (n,b) group on one XCD.
// grid = 72 * MB blocks, MB = M/64 (72 = 18 nblk * 4 b, divisible by 8).
// ---------------------------------------------------------------------------
__global__ __launch_bounds__(256) void gemm_mfma_kernel(
    const u16* __restrict__ Wh, const u16* __restrict__ Wl,
    const float* __restrict__ bias,
    const u16* __restrict__ XTh, const u16* __restrict__ XTl,
    float* __restrict__ Out, int M)
{
  __shared__ u16 wAh[2][64 * 40];   // 5120 B per buf
  __shared__ u16 wAl[2][64 * 40];
  const int MB = M >> 6;
  const int xcd = blockIdx.x & 7;
  const int idx = blockIdx.x >> 3;          // 0 .. 9*MB-1
  const int g = xcd * 9 + idx / MB;         // 0..71 group = (n_blk, b)
  const int mb = idx % MB;
  const int nb = g % 18, b = g / 18;
  const int m0 = mb * 64, n0 = nb * 128;
  const int tid = threadIdx.x;
  const int wv = tid >> 6, lane = tid & 63;
  const int lr = lane & 15, lg = lane >> 4;

  const u16* xbh = XTh + ((size_t)b * S_ + n0 + wv * 32) * 256;
  const u16* xbl = XTl + ((size_t)b * S_ + n0 + wv * 32) * 256;

  f32x4 acc[4][2];
#pragma unroll
  for (int mt = 0; mt < 4; mt++)
#pragma unroll
    for (int nt = 0; nt < 2; nt++) acc[mt][nt] = (f32x4){0.f, 0.f, 0.f, 0.f};

  // stage kstep t into buf
#define STAGE_W(t, buf)                                                      \
  {                                                                          \
    _Pragma("unroll")                                                        \
    for (int r = 0; r < 2; r++) {                                            \
      int id = tid + r * 256;                                                \
      int m = id >> 3, k4 = (id & 7) * 4;                                    \
      *(short4*)&wAh[buf][m * 40 + k4] =                                     \
          *(const short4*)&Wh[(size_t)(m0 + m) * 256 + (t) * 32 + k4];       \
      *(short4*)&wAl[buf][m * 40 + k4] =                                     \
          *(const short4*)&Wl[(size_t)(m0 + m) * 256 + (t) * 32 + k4];       \
    }                                                                        \
  }

  STAGE_W(0, 0);
  __syncthreads();

  for (int t = 0; t < 8; t++) {
    int buf = t & 1;
    if (t < 7) STAGE_W(t + 1, buf ^ 1);

    // B fragments direct from global
    bf16x8 bh[2], bl[2];
#pragma unroll
    for (int nt = 0; nt < 2; nt++) {
      size_t off = (size_t)(nt * 16 + lr) * 256 + t * 32 + lg * 8;
      bh[nt] = *(const bf16x8*)&xbh[off];
      bl[nt] = *(const bf16x8*)&xbl[off];
    }
    // A fragments from LDS
    bf16x8 ah[4], al[4];
#pragma unroll
    for (int mt = 0; mt < 4; mt++) {
      ah[mt] = *(const bf16x8*)&wAh[buf][(mt * 16 + lr) * 40 + lg * 8];
      al[mt] = *(const bf16x8*)&wAl[buf][(mt * 16 + lr) * 40 + lg * 8];
    }
#pragma unroll
    for (int mt = 0; mt < 4; mt++)
#pragma unroll
      for (int nt = 0; nt < 2; nt++) {
        acc[mt][nt] = __builtin_amdgcn_mfma_f32_16x16x32_bf16(ah[mt], bh[nt], acc[mt][nt], 0, 0, 0);
        acc[mt][nt] = __builtin_amdgcn_mfma_f32_16x16x32_bf16(ah[mt], bl[nt], acc[mt][nt], 0, 0, 0);
        acc[mt][nt] = __builtin_amdgcn_mfma_f32_16x16x32_bf16(al[mt], bh[nt], acc[mt][nt], 0, 0, 0);
      }
    __syncthreads();
  }

  // epilogue: D col = lane&15 (s), row = lg*4+reg (m)
  float* ob = Out + (size_t)b * M * S_;
#pragma unroll
  for (int mt = 0; mt < 4; mt++) {
    float4 b4 = *(const float4*)&bias[m0 + mt * 16 + lg * 4];
    float bv[4] = {b4.x, b4.y, b4.z, b4.w};
#pragma unroll
    for (int nt = 0; nt < 2; nt++) {
      int s = n0 + wv * 32 + nt * 16 + lr;
#pragma unroll
      for (int r = 0; r < 4; r++) {
        int m = m0 + mt * 16 + lg * 4 + r;
        ob[(size_t)m * S_ + s] = acc[mt][nt][r] + bv[r];
      }
    }
  }
#undef STAGE_W
}

// ---------------------------------------------------------------------------
// Row attention: per (b,n,h): S[i,w] = SCALE*sum_d rq[d,i,w]*rk[d,h,w],
// softmax over i (columns), store transposed bf16: arT[b,n,h][w][i].
// ---------------------------------------------------------------------------
__global__ __launch_bounds__(256) void row_attn_kernel(
    const float* __restrict__ rcv, u16* __restrict__ arT)
{
  __shared__ u16  rq[16 * 2304];     // [d][i*48+w]  73728 B
  __shared__ float rk[16 * 48];
  __shared__ float Sm[48 * 49];      // [i][w] padded
  __shared__ float cmax[48], crs[48];
  const int hg = blockIdx.x, n = blockIdx.y, b = blockIdx.z;
  const float* base = rcv + ((size_t)b * 768 + n * 96) * S_;  // rq; rk at +16*S_
  const int tid = threadIdx.x;

  for (int id = tid; id < 9216; id += 256) {     // 16*2304/4 float4s
    float4 v = *(const float4*)&base[id * 4];
    short4 s;
    s.x = (short)f2bf(v.x); s.y = (short)f2bf(v.y);
    s.z = (short)f2bf(v.z); s.w = (short)f2bf(v.w);
    *(short4*)&rq[id * 4] = s;
  }

  for (int hh = 0; hh < 6; hh++) {
    int h = hg * 6 + hh;
    for (int id = tid; id < 768; id += 256) {
      int d = id / 48, w = id % 48;
      rk[id] = base[(size_t)(16 + d) * S_ + h * 48 + w];
    }
    __syncthreads();
    for (int id = tid; id < 2304; id += 256) {
      int i = id / 48, w = id % 48;
      float s = 0.f;
#pragma unroll
      for (int d = 0; d < 16; d++)
        s += bf2f(rq[d * 2304 + i * 48 + w]) * rk[d * 48 + w];
      Sm[i * 49 + w] = s * 0.25f;
    }
    __syncthreads();
    if (tid < 48) {
      int w = tid;
      float m = -1e30f;
      for (int i = 0; i < 48; i++) m = fmaxf(m, Sm[i * 49 + w]);
      float s = 0.f;
      for (int i = 0; i < 48; i++) s += __expf(Sm[i * 49 + w] - m);
      cmax[w] = m; crs[w] = 1.0f / s;
    }
    __syncthreads();
    u16* dst = arT + ((size_t)(b * 8 + n) * 48 + h) * 2304;
    for (int id = tid; id < 2304; id += 256) {
      int w = id / 48, i = id % 48;
      float p = __expf(Sm[i * 49 + w] - cmax[w]) * crs[w];
      dst[id] = f2bf(p);                  // layout [w][i]
    }
    __syncthreads();
  }
}

// ---------------------------------------------------------------------------
// Col attention: per (b,n,h): T[w,j] = SCALE*sum_d ck[d,h,w]*cq[d,h,j],
// softmax over j (rows), store bf16: awT[b,n,h][w][j].
// ---------------------------------------------------------------------------
__global__ __launch_bounds__(256) void col_attn_kernel(
    const float* __restrict__ rcv, u16* __restrict__ awT)
{
  __shared__ float cq[16 * 48], ck[16 * 48];
  __shared__ float Tm[48 * 49];
  __shared__ float rmax[48], rrs[48];
  const int hg = blockIdx.x, n = blockIdx.y, b = blockIdx.z;
  const float* base = rcv + ((size_t)b * 768 + n * 96 + 32) * S_; // cq; ck at +16*S_
  const int tid = threadIdx.x;

  for (int hh = 0; hh < 6; hh++) {
    int h = hg * 6 + hh;
    for (int id = tid; id < 768; id += 256) {
      int d = id / 48, j = id % 48;
      cq[id] = base[(size_t)d * S_ + h * 48 + j];
      ck[id] = base[(size_t)(16 + d) * S_ + h * 48 + j];
    }
    __syncthreads();
    for (int id = tid; id < 2304; id += 256) {
      int w = id / 48, j = id % 48;
      float t = 0.f;
#pragma unroll
      for (int d = 0; d < 16; d++)
        t += ck[d * 48 + w] * cq[d * 48 + j];
      Tm[w * 49 + j] = t * 0.25f;
    }
    __syncthreads();
    if (tid < 48) {
      int w = tid;
      float m = -1e30f;
      for (int j = 0; j < 48; j++) m = fmaxf(m, Tm[w * 49 + j]);
      float s = 0.f;
      for (int j = 0; j < 48; j++) s += __expf(Tm[w * 49 + j] - m);
      rmax[w] = m; rrs[w] = 1.0f / s;
    }
    __syncthreads();
    u16* dst = awT + ((size_t)(b * 8 + n) * 48 + h) * 2304;
    for (int id = tid; id < 2304; id += 256) {
      int w = id / 48, j = id % 48;
      float p = __expf(Tm[w * 49 + j] - rmax[w]) * rrs[w];
      dst[id] = f2bf(p);                  // layout [w][j]
    }
    __syncthreads();
  }
}

// ---------------------------------------------------------------------------
// Main contraction + PE conv, wave-independent version (unchanged from r4).
// ---------------------------------------------------------------------------
__global__ __launch_bounds__(256) void attn_main_kernel(
    const float* __restrict__ rcv, const u16* __restrict__ arT,
    const u16* __restrict__ awT, const float* __restrict__ pe_w,
    const float* __restrict__ pe_b, float* __restrict__ y)
{
  __shared__ u16 vA[192 * 72];        // 27648 B  [(dloc,i)][j pad]
  const int id0 = blockIdx.x;
  const int n = id0 & 7;              // XCD swizzle
  const int rest = id0 >> 3;          // 0..127
  const int b = rest >> 5;            // 0..3
  const int inner = rest & 31;        // 0..31
  const int dchunk = inner >> 2;      // 0..7
  const int hc = inner & 3;           // 0..3
  const int h0 = hc * 12;
  const int tid = threadIdx.x;
  const int wave = tid >> 6, lane = tid & 63;
  const int lr = lane & 15, lg = lane >> 4;

  for (int id = tid; id < 192 * 24; id += 256) {
    int row = id / 24, col = 48 + id % 24;
    vA[row * 72 + col] = 0;
  }
  const float* vbase = rcv + ((size_t)b * 768 + n * 96 + 64 + dchunk * 4) * S_;
  for (int id = tid; id < 2304; id += 256) {   // 4 planes * 576 float4
    int dl = id / 576, rem = id % 576;
    int i = rem / 12, j4 = (rem % 12) * 4;
    float4 v = *(const float4*)&vbase[(size_t)dl * S_ + i * 48 + j4];
    short4 s;
    s.x = (short)f2bf(v.x); s.y = (short)f2bf(v.y);
    s.z = (short)f2bf(v.z); s.w = (short)f2bf(v.w);
    *(short4*)&vA[(dl * 48 + i) * 72 + j4] = s;
  }
  __syncthreads();   // the only barrier

  const size_t bnh0 = ((size_t)(b * 8 + n) * 48) * 2304;
  const int c = n * 32 + dchunk * 4 + wave;
  float pw[9];
#pragma unroll
  for (int t = 0; t < 9; t++) pw[t] = pe_w[c * 9 + t];
  const float pb = pe_b[c];
  float* yg = y + ((size_t)b * 256 + c) * S_;
  const int vrow0 = wave * 48;
  const bf16x8 zv = {0, 0, 0, 0, 0, 0, 0, 0};

  for (int hh = 0; hh < 12; hh++) {
    int h = h0 + hh;
    const u16* awg = awT + bnh0 + (size_t)h * 2304;  // [w][j]
    const u16* arg = arT + bnh0 + (size_t)h * 2304;  // [w][i]

    bf16x8 bf0[3], bf1[3];
#pragma unroll
    for (int nt = 0; nt < 3; nt++) {
      int row = (nt * 16 + lr) * 48;
      bf0[nt] = *(const bf16x8*)&awg[row + lg * 8];
      bf1[nt] = (lg < 2) ? *(const bf16x8*)&awg[row + 32 + lg * 8] : zv;
    }

    f32x4 acc[3][3];
#pragma unroll
    for (int mt = 0; mt < 3; mt++)
#pragma unroll
      for (int nt = 0; nt < 3; nt++) acc[mt][nt] = (f32x4){0.f, 0.f, 0.f, 0.f};

#pragma unroll
    for (int mt = 0; mt < 3; mt++) {
      bf16x8 a0 = *(const bf16x8*)&vA[(vrow0 + mt * 16 + lr) * 72 + lg * 8];
      bf16x8 a1 = *(const bf16x8*)&vA[(vrow0 + mt * 16 + lr) * 72 + 32 + lg * 8];
#pragma unroll
      for (int nt = 0; nt < 3; nt++) {
        acc[mt][nt] = __builtin_amdgcn_mfma_f32_16x16x32_bf16(a0, bf0[nt], acc[mt][nt], 0, 0, 0);
        acc[mt][nt] = __builtin_amdgcn_mfma_f32_16x16x32_bf16(a1, bf1[nt], acc[mt][nt], 0, 0, 0);
      }
    }

    float pv[3];
#pragma unroll
    for (int nt = 0; nt < 3; nt++) {
      int wrow = (nt * 16 + lr) * 48;
      float p = 0.f;
#pragma unroll
      for (int mt = 0; mt < 3; mt++) {
        short4 s = *(const short4*)&arg[wrow + mt * 16 + lg * 4];
        p += bf2f((u16)s.x) * acc[mt][nt][0] + bf2f((u16)s.y) * acc[mt][nt][1]
           + bf2f((u16)s.z) * acc[mt][nt][2] + bf2f((u16)s.w) * acc[mt][nt][3];
      }
      p += __shfl_xor(p, 16);
      p += __shfl_xor(p, 32);
      pv[nt] = p;
    }

    if (lane < 48) {
      float a = (lane < 16) ? pv[0] : (lane < 32 ? pv[1] : pv[2]);
      a += pb;
      int ww = lane;
#pragma unroll
      for (int kh = -1; kh <= 1; kh++) {
        int ih = h + kh;
        if (ih < 0 || ih > 47) continue;
#pragma unroll
        for (int kw = -1; kw <= 1; kw++) {
          int jw = ww + kw;
          if (jw < 0 || jw > 47) continue;
          a += pw[(kh + 1) * 3 + (kw + 1)] * bf2f(vA[(vrow0 + ih) * 72 + jw]);
        }
      }
      yg[h * 48 + ww] = a;
    }
  }
}

// ---------------------------------------------------------------------------
extern "C" void kernel_launch(void* const* d_in, const int* in_sizes, int n_in,
                              void* d_out, int out_size, void* d_ws, size_t ws_size,
                              hipStream_t stream) {
  const float* x      = (const float*)d_in[0];
  const float* rcv_w  = (const float*)d_in[1];
  const float* rcv_b  = (const float*)d_in[2];
  const float* pe_w   = (const float*)d_in[3];
  const float* pe_b   = (const float*)d_in[4];
  const float* proj_w = (const float*)d_in[5];
  const float* proj_b = (const float*)d_in[6];
  float* out = (float*)d_out;

  char* ws = (char*)d_ws;
  float* rcv = (float*)ws;                         // 28,311,552 B
  u16*   arT = (u16*)(ws + 28311552);              //  7,077,888 B
  u16*   awT = (u16*)(ws + 35389440);              //  7,077,888 B
  float* y   = (float*)(ws + 42467328);            //  9,437,184 B
  u16*   xTh = (u16*)(ws + 51904512);              //  4,718,592 B
  u16*   xTl = (u16*)(ws + 56623104);              //  4,718,592 B
  u16*   Whr = (u16*)(ws + 61341696);              //    393,216 B
  u16*   Wlr = (u16*)(ws + 61734912);              //    393,216 B
  u16*   Whp = (u16*)(ws + 62128128);              //    131,072 B
  u16*   Wlp = (u16*)(ws + 62259200);              //    131,072 B
  // yT aliases arT/awT region (free after attn_main)
  u16*   yTh = arT;
  u16*   yTl = awT;

  splitw_kernel<<<dim3(192), 256, 0, stream>>>(rcv_w, Whr, Wlr);
  splitw_kernel<<<dim3(64),  256, 0, stream>>>(proj_w, Whp, Wlp);
  split_transpose_kernel<<<dim3(36, 4, 4), 256, 0, stream>>>(x, xTh, xTl);
  gemm_mfma_kernel<<<dim3(72 * 12), 256, 0, stream>>>(Whr, Wlr, rcv_b, xTh, xTl, rcv, 768);
  row_attn_kernel<<<dim3(8, 8, 4), 256, 0, stream>>>(rcv, arT);
  col_attn_kernel<<<dim3(8, 8, 4), 256, 0, stream>>>(rcv, awT);
  attn_main_kernel<<<dim3(1024), 256, 0, stream>>>(rcv, arT, awT, pe_w, pe_b, y);
  split_transpose_kernel<<<dim3(36, 4, 4), 256, 0, stream>>>(y, yTh, yTl);
  gemm_mfma_kernel<<<dim3(72 * 4), 256, 0, stream>>>(Whp, Wlp, proj_b, yTh, yTl, out, 256);
}